// Round 3
// baseline (956.814 us; speedup 1.0000x reference)
//
#include <hip/hip_runtime.h>
#include <math.h>

namespace {

constexpr int BB  = 2;
constexpr int CC  = 64;
constexpr int HH  = 256;
constexpr int WW  = 512;
constexpr int OO  = 64;
constexpr int KK  = 9;
constexpr int PLANE = HH * WW;

__global__ __launch_bounds__(256, 2) void equiconv_kernel(
    const float* __restrict__ x, const float* __restrict__ wgt_g,
    const float* __restrict__ bias, float* __restrict__ out)
{
  const int tid = threadIdx.x;
  const int w   = blockIdx.x * 256 + tid;   // 0..511
  const int h   = blockIdx.y;               // 0..255
  const int b   = blockIdx.z;               // 0..1

  int   cidx[KK][4];
  float cw[KK][4];

  {
#pragma clang fp contract(off)
    // ---- bit-faithful replication of the reference's float32 chain ----
    const float TWO_PI_F = (float)(2.0 * M_PI);
    const float PI_F     = (float)M_PI;
    const float XS       = (float)(512.0 / (2.0 * M_PI));  // pano_W/(2π) as f32 scalar
    const float YS       = (float)(256.0 / M_PI);          // pano_H/π  as f32 scalar

    const float uf = (float)w, vf = (float)h;
    const float phi   = ((uf - 256.0f) / 512.0f) * TWO_PI_F;      // exact,exact,1-rnd
    const float theta = ((-(vf - 128.0f)) / 256.0f) * PI_F;       // exact,exact,1-rnd

    // correctly-rounded f32 transcendentals via f64
    const float sp = (float)sin((double)phi);
    const float cp = (float)cos((double)phi);
    const float st = (float)sin((double)theta);
    const float ct = (float)cos((double)theta);

    // ROT = Ry(phi) @ Rx(theta); every entry is a single f32 product (others exact 0/1)
    const float R00 = cp;        const float R01 = sp * st;  const float R02 = sp * ct;
    /* R10 = 0 */                const float R11 = ct;       const float R12 = -st;
    const float R20 = -sp;       const float R21 = cp * st;  const float R22 = cp * ct;

    // focal: pure Python-f64 math in the reference; rounded to f32 only at use
    const double focal_d = 1.5 / tan(0.5 * (3.0 * (2.0 * M_PI / 512.0)));
    const float  focal_f = (float)focal_d;

    for (int k = 0; k < KK; ++k) {
      const float wgk = (float)(k % 3) + 0.5f - 1.5f;  // exact -1,0,1
      const float hgk = (float)(k / 3) + 0.5f - 1.5f;  // exact -1,0,1

      // rays0 = [wg/focal, hg/focal, 1] / norm  (f32 divisions, axis-0 sum order)
      float rx0 = wgk / focal_f, ry0 = hgk / focal_f, rz0 = 1.0f;
      const float nrm = sqrtf(((rx0 * rx0) + (ry0 * ry0)) + (rz0 * rz0));
      rx0 = rx0 / nrm; ry0 = ry0 / nrm; rz0 = rz0 / nrm;

      // rays = ROT @ rays0, 3-term sums left-associated (einsum order)
      const float r0 = ((R00 * rx0) + (R01 * ry0)) + (R02 * rz0);
      const float r1 =               ((R11 * ry0)) + (R12 * rz0);   // R10*rx0 == 0
      const float r2 = ((R20 * rx0) + (R21 * ry0)) + (R22 * rz0);

      const float phi2 = (float)atan2((double)r0, (double)r2);
      float r1c = r1;
      if (r1c >  1.0f) r1c =  1.0f;
      if (r1c < -1.0f) r1c = -1.0f;
      const float th2 = (float)asin((double)r1c);

      const float xx = (XS * phi2) + 256.0f;
      const float yy = (YS * th2)  + 128.0f;

      // off_x = x - (wg+u); px = (u-1+kx) + off_x  — the reference's exact round-trip
      const float Ax = (float)(w + (k % 3) - 1);
      const float Ay = (float)(h + (k / 3) - 1);
      const float px = Ax + (xx - Ax);
      const float py = Ay + (yy - Ay);

      const float x0f = floorf(px), y0f = floorf(py);
      const float wx1 = px - x0f,   wy1 = py - y0f;
      const int ix0 = (int)x0f, iy0 = (int)y0f;
      const int ix1 = ix0 + 1,  iy1 = iy0 + 1;
      const bool vx0 = (ix0 >= 0) && (ix0 < WW);
      const bool vx1 = (ix1 >= 0) && (ix1 < WW);
      const bool vy0 = (iy0 >= 0) && (iy0 < HH);
      const bool vy1 = (iy1 >= 0) && (iy1 < HH);
      const int cx0 = min(max(ix0, 0), WW - 1);
      const int cx1 = min(max(ix1, 0), WW - 1);
      const int cy0 = min(max(iy0, 0), HH - 1);
      const int cy1 = min(max(iy1, 0), HH - 1);
      cidx[k][0] = cy0 * WW + cx0;
      cidx[k][1] = cy0 * WW + cx1;
      cidx[k][2] = cy1 * WW + cx0;
      cidx[k][3] = cy1 * WW + cx1;
      const float wy0f = 1.0f - wy1, wx0f = 1.0f - wx1;
      cw[k][0] = (wy0f * wx0f) * ((vy0 && vx0) ? 1.0f : 0.0f);
      cw[k][1] = (wy0f * wx1)  * ((vy0 && vx1) ? 1.0f : 0.0f);
      cw[k][2] = (wy1 * wx0f)  * ((vy1 && vx0) ? 1.0f : 0.0f);
      cw[k][3] = (wy1 * wx1)   * ((vy1 && vx1) ? 1.0f : 0.0f);
    }
  }

  float acc[OO];
#pragma unroll
  for (int o = 0; o < OO; ++o) acc[o] = 0.0f;

  const float* xb = x + (size_t)b * CC * PLANE;
#pragma unroll 1
  for (int c = 0; c < CC; ++c) {
    const float* xp = xb + (size_t)c * PLANE;
    float s[KK];
#pragma unroll
    for (int k = 0; k < KK; ++k) {
      s[k] = fmaf(cw[k][3], xp[cidx[k][3]],
             fmaf(cw[k][2], xp[cidx[k][2]],
             fmaf(cw[k][1], xp[cidx[k][1]],
                  cw[k][0] * xp[cidx[k][0]])));
    }
    // Weight indices are wave-uniform -> scalar loads; inner loop is pure v_fmac.
#pragma unroll
    for (int o = 0; o < OO; ++o) {
      const float* wp = wgt_g + ((size_t)o * CC + (size_t)c) * KK;
#pragma unroll
      for (int k = 0; k < KK; ++k) acc[o] = fmaf(s[k], wp[k], acc[o]);
    }
  }

  float* op = out + (size_t)b * OO * PLANE + (size_t)h * WW + w;
#pragma unroll
  for (int o = 0; o < OO; ++o) op[(size_t)o * PLANE] = acc[o] + bias[o];
}

} // namespace

extern "C" void kernel_launch(void* const* d_in, const int* in_sizes, int n_in,
                              void* d_out, int out_size, void* d_ws, size_t ws_size,
                              hipStream_t stream) {
  const float* x      = (const float*)d_in[0];
  const float* weight = (const float*)d_in[1];
  const float* bias   = (const float*)d_in[2];
  float* out          = (float*)d_out;

  dim3 grid(WW / 256, HH, BB);
  dim3 block(256);
  hipLaunchKernelGGL(equiconv_kernel, grid, block, 0, stream, x, weight, bias, out);
}

// Round 4
// 584.120 us; speedup vs baseline: 1.6380x; 1.6380x over previous
//
#include <hip/hip_runtime.h>
#include <math.h>

namespace {

constexpr int BB  = 2;
constexpr int CC  = 64;
constexpr int HH  = 256;
constexpr int WW  = 512;
constexpr int OO  = 64;
constexpr int KK  = 9;
constexpr int PLANE = HH * WW;

// Staged row window: |py - h| <= 81.49*atan(sqrt(2)/focal) = 1.415  =>
// iy0 in [h-2,h+1], iy1 in [h-1,h+2]  =>  rows [h-2, h+2] suffice (5 rows).
// Pad to 6 rows so the buffer is 12 KB = 12 uniform 1 KB chunks (3 per wave).
constexpr int SROWS = 6;
constexpr int BUF_F = SROWS * WW;  // 3072 floats

__global__ __launch_bounds__(256, 3) void equiconv_kernel(
    const float* __restrict__ x, const float* __restrict__ wgt_g,
    const float* __restrict__ bias, float* __restrict__ out)
{
  __shared__ float lbuf[2][BUF_F];

  const int tid  = threadIdx.x;
  const int wid  = tid >> 6;
  const int lane = tid & 63;
  const int w    = blockIdx.x * 256 + tid;  // 0..511
  const int h    = blockIdx.y;              // 0..255
  const int b    = blockIdx.z;              // 0..1

  int   jx[KK][4];   // LDS float indices into the 6x512 staged window
  float cw[KK][4];

  {
#pragma clang fp contract(off)
    // ---- bit-faithful replication of the reference's float32 chain ----
    const float TWO_PI_F = (float)(2.0 * M_PI);
    const float PI_F     = (float)M_PI;
    const float XS       = (float)(512.0 / (2.0 * M_PI));
    const float YS       = (float)(256.0 / M_PI);

    const float uf = (float)w, vf = (float)h;
    const float phi   = ((uf - 256.0f) / 512.0f) * TWO_PI_F;
    const float theta = ((-(vf - 128.0f)) / 256.0f) * PI_F;

    const float sp = (float)sin((double)phi);
    const float cp = (float)cos((double)phi);
    const float st = (float)sin((double)theta);
    const float ct = (float)cos((double)theta);

    const float R00 = cp;        const float R01 = sp * st;  const float R02 = sp * ct;
    /* R10 = 0 */                const float R11 = ct;       const float R12 = -st;
    const float R20 = -sp;       const float R21 = cp * st;  const float R22 = cp * ct;

    const double focal_d = 1.5 / tan(0.5 * (3.0 * (2.0 * M_PI / 512.0)));
    const float  focal_f = (float)focal_d;

    for (int k = 0; k < KK; ++k) {
      const float wgk = (float)(k % 3) + 0.5f - 1.5f;
      const float hgk = (float)(k / 3) + 0.5f - 1.5f;

      float rx0 = wgk / focal_f, ry0 = hgk / focal_f, rz0 = 1.0f;
      const float nrm = sqrtf(((rx0 * rx0) + (ry0 * ry0)) + (rz0 * rz0));
      rx0 = rx0 / nrm; ry0 = ry0 / nrm; rz0 = rz0 / nrm;

      const float r0 = ((R00 * rx0) + (R01 * ry0)) + (R02 * rz0);
      const float r1 =               ((R11 * ry0)) + (R12 * rz0);
      const float r2 = ((R20 * rx0) + (R21 * ry0)) + (R22 * rz0);

      const float phi2 = (float)atan2((double)r0, (double)r2);
      float r1c = r1;
      if (r1c >  1.0f) r1c =  1.0f;
      if (r1c < -1.0f) r1c = -1.0f;
      const float th2 = (float)asin((double)r1c);

      const float xx = (XS * phi2) + 256.0f;
      const float yy = (YS * th2)  + 128.0f;

      const float Ax = (float)(w + (k % 3) - 1);
      const float Ay = (float)(h + (k / 3) - 1);
      const float px = Ax + (xx - Ax);
      const float py = Ay + (yy - Ay);

      const float x0f = floorf(px), y0f = floorf(py);
      const float wx1 = px - x0f,   wy1 = py - y0f;
      const int ix0 = (int)x0f, iy0 = (int)y0f;
      const int ix1 = ix0 + 1,  iy1 = iy0 + 1;
      const bool vx0 = (ix0 >= 0) && (ix0 < WW);
      const bool vx1 = (ix1 >= 0) && (ix1 < WW);
      const bool vy0 = (iy0 >= 0) && (iy0 < HH);
      const bool vy1 = (iy1 >= 0) && (iy1 < HH);
      const int cx0 = min(max(ix0, 0), WW - 1);
      const int cx1 = min(max(ix1, 0), WW - 1);
      const int cy0 = min(max(iy0, 0), HH - 1);
      const int cy1 = min(max(iy1, 0), HH - 1);
      // LDS-local row index: staged row j holds plane row clamp(h-2+j); for any
      // clamped cy in [max(0,h-2), min(255,h+2)], j = cy-h+2 lands on that row.
      const int j0 = cy0 - h + 2;
      const int j1 = cy1 - h + 2;
      jx[k][0] = j0 * WW + cx0;
      jx[k][1] = j0 * WW + cx1;
      jx[k][2] = j1 * WW + cx0;
      jx[k][3] = j1 * WW + cx1;
      const float wy0f = 1.0f - wy1, wx0f = 1.0f - wx1;
      cw[k][0] = (wy0f * wx0f) * ((vy0 && vx0) ? 1.0f : 0.0f);
      cw[k][1] = (wy0f * wx1)  * ((vy0 && vx1) ? 1.0f : 0.0f);
      cw[k][2] = (wy1 * wx0f)  * ((vy1 && vx0) ? 1.0f : 0.0f);
      cw[k][3] = (wy1 * wx1)   * ((vy1 && vx1) ? 1.0f : 0.0f);
    }
  }

  float acc[OO];
#pragma unroll
  for (int o = 0; o < OO; ++o) acc[o] = 0.0f;

  const float* xb = x + (size_t)b * CC * PLANE;

  // Stage channel c's rows [h-2, h+3] (clamped) into lbuf[bi]: 12 chunks of
  // 1 KB, 3 per wave, via global_load_lds width-16 (LDS dest = wave-uniform
  // base + lane*16; our layout is linear so this matches).
  auto stage = [&](int bi, int c) {
    const float* xp = xb + (size_t)c * PLANE;
#pragma unroll
    for (int i = 0; i < 3; ++i) {
      const int c3   = wid + i * 4;          // 0..11, wave-uniform
      const int j    = c3 >> 1;
      const int half = c3 & 1;
      const int srow = min(max(h - 2 + j, 0), HH - 1);
      const float* src = xp + srow * WW + half * 256 + lane * 4;  // 16 B/lane
      __builtin_amdgcn_global_load_lds(
          (const __attribute__((address_space(1))) void*)src,
          (__attribute__((address_space(3))) void*)&lbuf[bi][c3 * 256],
          16, 0, 0);
    }
  };

  stage(0, 0);

#pragma unroll 1
  for (int c = 0; c < CC; ++c) {
    const int bi = c & 1;
    if (c + 1 < CC) {
      stage(bi ^ 1, c + 1);                       // 3 more in flight (6 total)
      asm volatile("s_waitcnt vmcnt(3)" ::: "memory");  // drain stage(c) only
    } else {
      asm volatile("s_waitcnt vmcnt(0)" ::: "memory");
    }
    __builtin_amdgcn_s_barrier();   // all waves' stage(c) visible
    asm volatile("" ::: "memory");

    const float* L = lbuf[bi];
    float s[KK];
#pragma unroll
    for (int k = 0; k < KK; ++k) {
      s[k] = fmaf(cw[k][3], L[jx[k][3]],
             fmaf(cw[k][2], L[jx[k][2]],
             fmaf(cw[k][1], L[jx[k][1]],
                  cw[k][0] * L[jx[k][0]])));
    }
    // Wave-uniform weight addresses -> scalar loads; inner loop pure v_fmac.
#pragma unroll
    for (int o = 0; o < OO; ++o) {
      const float* wp = wgt_g + ((size_t)o * CC + (size_t)c) * KK;
#pragma unroll
      for (int k = 0; k < KK; ++k) acc[o] = fmaf(s[k], wp[k], acc[o]);
    }

    asm volatile("" ::: "memory");
    __builtin_amdgcn_s_barrier();   // all waves done reading lbuf[bi]
  }

  float* op = out + (size_t)b * OO * PLANE + (size_t)h * WW + w;
#pragma unroll
  for (int o = 0; o < OO; ++o) op[(size_t)o * PLANE] = acc[o] + bias[o];
}

} // namespace

extern "C" void kernel_launch(void* const* d_in, const int* in_sizes, int n_in,
                              void* d_out, int out_size, void* d_ws, size_t ws_size,
                              hipStream_t stream) {
  const float* x      = (const float*)d_in[0];
  const float* weight = (const float*)d_in[1];
  const float* bias   = (const float*)d_in[2];
  float* out          = (float*)d_out;

  dim3 grid(WW / 256, HH, BB);
  dim3 block(256);
  hipLaunchKernelGGL(equiconv_kernel, grid, block, 0, stream, x, weight, bias, out);
}